// Round 8
// baseline (420.684 us; speedup 1.0000x reference)
//
#include <hip/hip_runtime.h>

#define N_NODES 100000
#define N_EDGESC 800000
#define HID 128
#define NGRAPH 128
#define BN_EPS 1e-5f
#define SCAN_BLOCKS ((N_NODES + 1023) / 1024)   // 98
#define NREP 32   // BN-stats atomic replicas
#define PS 136    // LDS row stride in shorts: 272B = 16B-aligned
#define MLP_GRID 521   // 1563 tiles / 521 = exactly 3 per block
#define EPB 2048       // edges per fill/count block
#define ECHUNKS ((N_EDGESC + EPB - 1) / EPB)    // 391
#define NXCD 12500     // nodes per XCD partition (100000/8)
#define NGRP 50000     // balanced gather groups (~16 edges each)

typedef __bf16 bf16x8 __attribute__((ext_vector_type(8)));
typedef float f32x4 __attribute__((ext_vector_type(4)));

__device__ inline unsigned short f2bf(float f) {     // RNE fp32 -> bf16
    unsigned int u = __float_as_uint(f);
    unsigned int r = u + 0x7FFFu + ((u >> 16) & 1u);
    return (unsigned short)(r >> 16);
}
__device__ inline float b2f(unsigned short u) {
    return __uint_as_float(((unsigned int)u) << 16);
}

// ================= CSR build (XCD-partitioned scatter) =================
// Block b: edge chunk b>>3, only edges with dst in range (b&7)*NXCD..+NXCD.
// With round-robin blockIdx->XCD dispatch, each deg/cursor/eidx region is
// written by one XCD only -> lines complete in local L2, single writeback.
__global__ __launch_bounds__(256) void k_count(const int* __restrict__ dst,
                                               int* __restrict__ deg)
{
    const int xcd = blockIdx.x & 7;
    const int chunk = blockIdx.x >> 3;
    const int lo = xcd * NXCD, hi = lo + NXCD;
    #pragma unroll
    for (int i = 0; i < EPB / 256; ++i) {
        int e = chunk * EPB + i * 256 + threadIdx.x;
        if (e < N_EDGESC) {
            int d = dst[e];
            if (d >= lo && d < hi) atomicAdd(&deg[d], 1);
        }
    }
}

__global__ __launch_bounds__(256) void k_scan_block(const int* __restrict__ deg,
    int* __restrict__ off, int* __restrict__ bsum)
{
    __shared__ int ts[256];
    int base = blockIdx.x * 1024 + threadIdx.x * 4;
    int v[4], s = 0;
    #pragma unroll
    for (int i = 0; i < 4; ++i) {
        int idx = base + i;
        v[i] = (idx < N_NODES) ? deg[idx] : 0;
        s += v[i];
    }
    ts[threadIdx.x] = s;
    __syncthreads();
    for (int d = 1; d < 256; d <<= 1) {
        int t = (threadIdx.x >= d) ? ts[threadIdx.x - d] : 0;
        __syncthreads();
        ts[threadIdx.x] += t;
        __syncthreads();
    }
    int run = ts[threadIdx.x] - s;
    #pragma unroll
    for (int i = 0; i < 4; ++i) {
        int idx = base + i;
        if (idx < N_NODES) off[idx] = run;
        run += v[i];
    }
    if (threadIdx.x == 255) bsum[blockIdx.x] = ts[255];
}

__global__ void k_scan_top(int* __restrict__ bsum, int* __restrict__ off)
{
    int run = 0;
    for (int i = 0; i < SCAN_BLOCKS; ++i) { int t = bsum[i]; bsum[i] = run; run += t; }
    off[N_NODES] = run;
}

__global__ __launch_bounds__(256) void k_scan_add(int* __restrict__ off,
    const int* __restrict__ bsum, int* __restrict__ cursor)
{
    int i = blockIdx.x * 256 + threadIdx.x;
    if (i < N_NODES) {
        int o = off[i] + bsum[i >> 10];
        off[i] = o;
        cursor[i] = o;
    }
}

__global__ __launch_bounds__(256) void k_fill(const int* __restrict__ src,
    const int* __restrict__ dst, int* __restrict__ cursor, int* __restrict__ eidx)
{
    const int xcd = blockIdx.x & 7;
    const int chunk = blockIdx.x >> 3;
    const int lo = xcd * NXCD, hi = lo + NXCD;
    #pragma unroll
    for (int i = 0; i < EPB / 256; ++i) {
        int e = chunk * EPB + i * 256 + threadIdx.x;
        if (e < N_EDGESC) {
            int d = dst[e];
            if (d >= lo && d < hi) {
                int p = atomicAdd(&cursor[d], 1);
                eidx[p] = src[e];
            }
        }
    }
}

// balanced gather partition: part[i] = first node of group i
// (smallest n with off[n] >= i*E/NGRP)
__global__ __launch_bounds__(256) void k_part(const int* __restrict__ off,
    int* __restrict__ part)
{
    int i = blockIdx.x * 256 + threadIdx.x;
    if (i > NGRP) return;
    long long target = (long long)i * N_EDGESC / NGRP;
    int lo = 0, hi = N_NODES;
    while (lo < hi) {
        int mid = (lo + hi) >> 1;
        if ((long long)off[mid] < target) lo = mid + 1; else hi = mid;
    }
    part[i] = lo;
}

// ================ dtype conversion ================
__global__ __launch_bounds__(256) void k_cvt(const float* __restrict__ X,
    unsigned short* __restrict__ Y, int n4)
{
    int i = blockIdx.x * 256 + threadIdx.x;
    if (i < n4) {
        float4 v = ((const float4*)X)[i];
        ((ushort4*)Y)[i] = make_ushort4(f2bf(v.x), f2bf(v.y), f2bf(v.z), f2bf(v.w));
    }
}

__global__ __launch_bounds__(256) void k_wcvt4(const float* __restrict__ Wa,
    const float* __restrict__ Wb, const float* __restrict__ Wc,
    const float* __restrict__ Wd, unsigned short* __restrict__ WT)
{
    int idx = blockIdx.x * 256 + threadIdx.x;   // 256 blocks -> 65536
    int mat = idx >> 14, w = idx & 16383;
    int k = w >> 7, n = w & 127;
    const float* W = (mat == 0) ? Wa : (mat == 1) ? Wb : (mat == 2) ? Wc : Wd;
    WT[mat * 16384 + n * 128 + k] = f2bf(W[w]);
}

// ====== balanced gather: per-group node range, ~equal edges per group ======
// 16 lanes per group, uint4 = 8 bf16 (16B) per lane; 8-way edge ILP.
template<bool BN>
__device__ inline void acc_row(float* acc, uint4 v,
                               const float* sc, const float* sh)
{
    unsigned int u[4] = {v.x, v.y, v.z, v.w};
    #pragma unroll
    for (int j = 0; j < 4; ++j) {
        float lo = b2f((unsigned short)u[j]);
        float hi = b2f((unsigned short)(u[j] >> 16));
        if (BN) {
            lo = fmaxf(lo * sc[2*j]   + sh[2*j],   0.f);
            hi = fmaxf(hi * sc[2*j+1] + sh[2*j+1], 0.f);
        }
        acc[2*j]   += lo;
        acc[2*j+1] += hi;
    }
}

template<bool BN>
__global__ __launch_bounds__(256) void k_gather(
    const unsigned short* __restrict__ X, const float* __restrict__ SC,
    const int* __restrict__ off, const int* __restrict__ eidx,
    const int* __restrict__ part, unsigned short* __restrict__ OUT)
{
    int gi = blockIdx.x * 16 + (threadIdx.x >> 4);
    if (gi >= NGRP) return;
    const int lane = threadIdx.x & 15;
    const size_t co = (size_t)lane * 8;

    float sc[8], sh[8];
    if (BN) {
        *(float4*)&sc[0] = ((const float4*)SC)[lane * 2];
        *(float4*)&sc[4] = ((const float4*)SC)[lane * 2 + 1];
        *(float4*)&sh[0] = ((const float4*)SC)[32 + lane * 2];
        *(float4*)&sh[4] = ((const float4*)SC)[32 + lane * 2 + 1];
    }

    const int nbeg = part[gi], nend = part[gi + 1];
    for (int n = nbeg; n < nend; ++n) {
        float acc[8] = {0.f, 0.f, 0.f, 0.f, 0.f, 0.f, 0.f, 0.f};
        acc_row<BN>(acc, *(const uint4*)(X + (size_t)n * HID + co), sc, sh);

        int k = off[n], kend = off[n + 1];
        for (; k + 7 < kend; k += 8) {       // 8-way ILP: 128B in flight/lane
            uint4 v0 = *(const uint4*)(X + (size_t)eidx[k]   * HID + co);
            uint4 v1 = *(const uint4*)(X + (size_t)eidx[k+1] * HID + co);
            uint4 v2 = *(const uint4*)(X + (size_t)eidx[k+2] * HID + co);
            uint4 v3 = *(const uint4*)(X + (size_t)eidx[k+3] * HID + co);
            uint4 v4 = *(const uint4*)(X + (size_t)eidx[k+4] * HID + co);
            uint4 v5 = *(const uint4*)(X + (size_t)eidx[k+5] * HID + co);
            uint4 v6 = *(const uint4*)(X + (size_t)eidx[k+6] * HID + co);
            uint4 v7 = *(const uint4*)(X + (size_t)eidx[k+7] * HID + co);
            acc_row<BN>(acc, v0, sc, sh); acc_row<BN>(acc, v1, sc, sh);
            acc_row<BN>(acc, v2, sc, sh); acc_row<BN>(acc, v3, sc, sh);
            acc_row<BN>(acc, v4, sc, sh); acc_row<BN>(acc, v5, sc, sh);
            acc_row<BN>(acc, v6, sc, sh); acc_row<BN>(acc, v7, sc, sh);
        }
        for (; k + 3 < kend; k += 4) {
            uint4 v0 = *(const uint4*)(X + (size_t)eidx[k]   * HID + co);
            uint4 v1 = *(const uint4*)(X + (size_t)eidx[k+1] * HID + co);
            uint4 v2 = *(const uint4*)(X + (size_t)eidx[k+2] * HID + co);
            uint4 v3 = *(const uint4*)(X + (size_t)eidx[k+3] * HID + co);
            acc_row<BN>(acc, v0, sc, sh); acc_row<BN>(acc, v1, sc, sh);
            acc_row<BN>(acc, v2, sc, sh); acc_row<BN>(acc, v3, sc, sh);
        }
        for (; k < kend; ++k) {
            uint4 v = *(const uint4*)(X + (size_t)eidx[k] * HID + co);
            acc_row<BN>(acc, v, sc, sh);
        }

        uint4 o;
        o.x = (unsigned int)f2bf(acc[0]) | ((unsigned int)f2bf(acc[1]) << 16);
        o.y = (unsigned int)f2bf(acc[2]) | ((unsigned int)f2bf(acc[3]) << 16);
        o.z = (unsigned int)f2bf(acc[4]) | ((unsigned int)f2bf(acc[5]) << 16);
        o.w = (unsigned int)f2bf(acc[6]) | ((unsigned int)f2bf(acc[7]) << 16);
        *(uint4*)(OUT + (size_t)n * HID + co) = o;
    }
}

// ============== persistent fused MLP with cross-tile prefetch ==============
// Grid-stride over 64-row tiles (3 per block). Wave-private LDS; NO barriers
// (barriers would force vmcnt(0) drain, killing the A-prefetch). Same-wave
// DS write->read ordering is guaranteed (aliasing dep + in-order DS pipe).
__global__ __launch_bounds__(256) void k_mlp(
    const unsigned short* __restrict__ A,
    const unsigned short* __restrict__ WTa, const float* __restrict__ ba,
    const unsigned short* __restrict__ WTb, const float* __restrict__ bb,
    unsigned short* __restrict__ Cb, float* __restrict__ Srep, int M)
{
    __shared__ unsigned short Hs[4][16 * PS];

    const int tid = threadIdx.x;
    const int wave = tid >> 6;
    const int lane = tid & 63;
    const int m = lane & 15;
    const int quad = lane >> 4;
    unsigned short* lds = Hs[wave];
    const int ntiles = (M + 63) / 64;

    float bav[8], bbv[8];
    #pragma unroll
    for (int n0 = 0; n0 < 8; ++n0) { bav[n0] = ba[n0*16+m]; bbv[n0] = bb[n0*16+m]; }

    float s[8] = {0,0,0,0,0,0,0,0}, s2[8] = {0,0,0,0,0,0,0,0};

    int t = blockIdx.x;
    bf16x8 aN[4];
    if (t < ntiles) {
        const unsigned short* arow = A + (size_t)(t*64 + wave*16 + m) * HID + quad*8;
        #pragma unroll
        for (int kk = 0; kk < 4; ++kk) aN[kk] = *(const bf16x8*)(arow + kk*32);
    }

    for (; t < ntiles; t += MLP_GRID) {
        bf16x8 a[4];
        #pragma unroll
        for (int kk = 0; kk < 4; ++kk) a[kk] = aN[kk];

        int tn = t + MLP_GRID;               // prefetch next tile's A-frags
        if (tn < ntiles) {
            const unsigned short* arow = A + (size_t)(tn*64 + wave*16 + m) * HID + quad*8;
            #pragma unroll
            for (int kk = 0; kk < 4; ++kk) aN[kk] = *(const bf16x8*)(arow + kk*32);
        }

        // ---- GEMM-a ----
        f32x4 acc[8];
        #pragma unroll
        for (int n0 = 0; n0 < 8; ++n0) acc[n0] = {0.f, 0.f, 0.f, 0.f};
        #pragma unroll
        for (int kk = 0; kk < 4; ++kk) {
            #pragma unroll
            for (int n0 = 0; n0 < 8; ++n0) {
                bf16x8 b = *(const bf16x8*)(WTa + (size_t)(n0*16+m)*HID + quad*8 + kk*32);
                acc[n0] = __builtin_amdgcn_mfma_f32_16x16x32_bf16(a[kk], b, acc[n0], 0, 0, 0);
            }
        }

        // hidden = relu(acc + bias) -> wave-private LDS
        #pragma unroll
        for (int n0 = 0; n0 < 8; ++n0)
            #pragma unroll
            for (int r = 0; r < 4; ++r)
                lds[(quad*4+r)*PS + n0*16+m] = f2bf(fmaxf(acc[n0][r] + bav[n0], 0.f));
        __builtin_amdgcn_sched_barrier(0);

        bf16x8 hfr[4];
        #pragma unroll
        for (int kk = 0; kk < 4; ++kk)
            hfr[kk] = *(const bf16x8*)(lds + m*PS + quad*8 + kk*32);
        __builtin_amdgcn_sched_barrier(0);

        // ---- GEMM-b ----
        #pragma unroll
        for (int n0 = 0; n0 < 8; ++n0) acc[n0] = {0.f, 0.f, 0.f, 0.f};
        #pragma unroll
        for (int kk = 0; kk < 4; ++kk) {
            #pragma unroll
            for (int n0 = 0; n0 < 8; ++n0) {
                bf16x8 b = *(const bf16x8*)(WTb + (size_t)(n0*16+m)*HID + quad*8 + kk*32);
                acc[n0] = __builtin_amdgcn_mfma_f32_16x16x32_bf16(hfr[kk], b, acc[n0], 0, 0, 0);
            }
        }

        // ---- epilogue: bias, stats, bf16 -> LDS, coalesced store ----
        const int rowbase = t*64 + wave*16;
        bool full = (rowbase + 16 <= M);
        #pragma unroll
        for (int n0 = 0; n0 < 8; ++n0) {
            #pragma unroll
            for (int r = 0; r < 4; ++r) {
                float v = acc[n0][r] + bbv[n0];
                if (full || rowbase + quad*4 + r < M) { s[n0] += v; s2[n0] += v*v; }
                lds[(quad*4+r)*PS + n0*16+m] = f2bf(v);
            }
        }
        __builtin_amdgcn_sched_barrier(0);
        #pragma unroll
        for (int it = 0; it < 4; ++it) {
            int idx = it*64 + lane;
            int row = idx >> 4, chunk = idx & 15;
            uint4 v = *(const uint4*)(lds + row*PS + chunk*8);
            int g = rowbase + row;
            if (g < M) *(uint4*)(Cb + (size_t)g*HID + chunk*8) = v;
        }
        __builtin_amdgcn_sched_barrier(0);
    }

    // ---- once per block: reduce stats over quads, atomics into replicas ----
    #pragma unroll
    for (int n0 = 0; n0 < 8; ++n0) {
        s[n0]  += __shfl_xor(s[n0], 16, 64);
        s[n0]  += __shfl_xor(s[n0], 32, 64);
        s2[n0] += __shfl_xor(s2[n0], 16, 64);
        s2[n0] += __shfl_xor(s2[n0], 32, 64);
    }
    if (quad == 0) {
        float* R = Srep + (size_t)((blockIdx.x * 4 + wave) & (NREP - 1)) * 256;
        #pragma unroll
        for (int n0 = 0; n0 < 8; ++n0) {
            atomicAdd(&R[n0*16+m], s[n0]);
            atomicAdd(&R[128 + n0*16+m], s2[n0]);
        }
    }
}

__global__ void k_bnfinalize(const float* __restrict__ Srep,
    const float* __restrict__ gamma, const float* __restrict__ beta,
    float* __restrict__ SC, int M)
{
    int f = threadIdx.x;   // 128
    float s = 0.f, s2 = 0.f;
    for (int r = 0; r < NREP; ++r) {
        s += Srep[r * 256 + f];
        s2 += Srep[r * 256 + 128 + f];
    }
    float mean = s / (float)M;
    float var = s2 / (float)M - mean * mean;
    var = fmaxf(var, 0.f);
    float sc = gamma[f] * rsqrtf(var + BN_EPS);
    SC[f] = sc;
    SC[HID + f] = beta[f] - mean * sc;
}

// ---------------- pooling (fused BN+ReLU) ----------------
__global__ void k_bounds(const int* __restrict__ batch, int* __restrict__ gstart)
{
    int g = threadIdx.x;
    int lo = 0, hi = N_NODES;
    while (lo < hi) {
        int mid = (lo + hi) >> 1;
        if (batch[mid] < g) lo = mid + 1; else hi = mid;
    }
    gstart[g] = lo;
    if (g == 0) gstart[NGRAPH] = N_NODES;
}

__global__ __launch_bounds__(256) void k_pool(const unsigned short* __restrict__ H,
    const float* __restrict__ SC, const int* __restrict__ gstart,
    float* __restrict__ P)
{
    int g = blockIdx.x >> 4, part = blockIdx.x & 15;
    int beg = gstart[g], end = gstart[g + 1];
    int f = threadIdx.x & 127, half = threadIdx.x >> 7;
    float sc = SC[f], sh = SC[HID + f];
    float s = 0.f;
    for (int r = beg + part * 2 + half; r < end; r += 32)
        s += fmaxf(b2f(H[(size_t)r * HID + f]) * sc + sh, 0.f);
    __shared__ float ls[256];
    ls[threadIdx.x] = s;
    __syncthreads();
    if (threadIdx.x < 128)
        atomicAdd(&P[g * HID + threadIdx.x], ls[threadIdx.x] + ls[threadIdx.x + 128]);
}

// ---------------- classifier head + log_softmax ----------------
__global__ void k_head(const float* __restrict__ P, const int* __restrict__ gstart,
    const float* __restrict__ Wlin, const float* __restrict__ blin,
    float* __restrict__ out)
{
    int g = blockIdx.x;
    int l = threadIdx.x;    // 64 lanes
    float inv = 1.f / (float)max(gstart[g + 1] - gstart[g], 1);
    float p0 = P[(size_t)g * HID + l] * inv;
    float p1 = P[(size_t)g * HID + 64 + l] * inv;
    float lg[10];
    #pragma unroll
    for (int c = 0; c < 10; ++c) {
        float v = p0 * Wlin[l * 10 + c] + p1 * Wlin[(64 + l) * 10 + c];
        #pragma unroll
        for (int off = 32; off > 0; off >>= 1) v += __shfl_down(v, off);
        lg[c] = v;
    }
    if (l == 0) {
        float mx = -1e30f;
        #pragma unroll
        for (int c = 0; c < 10; ++c) { lg[c] += blin[c]; mx = fmaxf(mx, lg[c]); }
        float s = 0.f;
        #pragma unroll
        for (int c = 0; c < 10; ++c) s += expf(lg[c] - mx);
        float lse = mx + logf(s);
        #pragma unroll
        for (int c = 0; c < 10; ++c) out[g * 10 + c] = lg[c] - lse;
    }
}

extern "C" void kernel_launch(void* const* d_in, const int* in_sizes, int n_in,
                              void* d_out, int out_size, void* d_ws, size_t ws_size,
                              hipStream_t stream)
{
    const float* x    = (const float*)d_in[0];
    const int*   ei   = (const int*)d_in[1];
    const int*   batch= (const int*)d_in[2];
    const float* W1a  = (const float*)d_in[3];
    const float* b1a  = (const float*)d_in[4];
    const float* W1b  = (const float*)d_in[5];
    const float* b1b  = (const float*)d_in[6];
    const float* g1   = (const float*)d_in[7];
    const float* be1  = (const float*)d_in[8];
    const float* W2a  = (const float*)d_in[9];
    const float* b2a  = (const float*)d_in[10];
    const float* W2b  = (const float*)d_in[11];
    const float* b2b  = (const float*)d_in[12];
    const float* g2   = (const float*)d_in[13];
    const float* be2  = (const float*)d_in[14];
    const float* Wl   = (const float*)d_in[15];
    const float* bl   = (const float*)d_in[16];
    float* out = (float*)d_out;

    const int* src = ei;
    const int* dst = ei + N_EDGESC;

    const size_t NM = (size_t)N_NODES * HID;    // 12.8M
    char* wsb = (char*)d_ws;
    // Ab first: k_mlp overreads 32 rows past Ab -> lands in Yb (valid).
    unsigned short* Ab  = (unsigned short*)wsb;                 // NM u16 (agg out)
    unsigned short* Yb  = Ab + NM;                              // NM u16 (Cb1)
    unsigned short* Xb  = Yb + NM;                              // NM u16 (x / Cb2)
    float* Srep1 = (float*)(Xb + NM);                           // NREP*256
    float* Srep2 = Srep1 + NREP * 256;                          // NREP*256
    float* SC1  = Srep2 + NREP * 256;                           // 256
    float* SC2  = SC1 + 256;                                    // 256
    float* P    = SC2 + 256;                                    // 128*128
    unsigned short* WT = (unsigned short*)(P + (size_t)NGRAPH * HID); // 4*16384 u16
    int* deg    = (int*)(WT + 4 * 16384);
    int* off    = deg + N_NODES;          // N_NODES+1
    int* cursor = off + N_NODES + 1;      // N_NODES
    int* bsum   = cursor + N_NODES;       // SCAN_BLOCKS
    int* eidx   = bsum + SCAN_BLOCKS;     // N_EDGESC
    int* gstart = eidx + N_EDGESC;        // NGRAPH+1
    int* part   = gstart + NGRAPH + 1;    // NGRP+1

    dim3 blk(256);
    const int nodeBlocks = (N_NODES + 255) / 256;      // 391
    const int gatBlocks  = (NGRP + 15) / 16;           // 3125
    const int cvtBlocks = (int)(NM / 4 + 255) / 256;   // 12500

    // ---- CSR build + conversions ----
    hipMemsetAsync(deg, 0, N_NODES * sizeof(int), stream);
    hipMemsetAsync(P, 0, (size_t)NGRAPH * HID * sizeof(float), stream);
    hipMemsetAsync(Srep1, 0, 2 * NREP * 256 * sizeof(float), stream);
    k_count<<<ECHUNKS * 8, blk, 0, stream>>>(dst, deg);
    k_scan_block<<<SCAN_BLOCKS, blk, 0, stream>>>(deg, off, bsum);
    k_scan_top<<<1, 1, 0, stream>>>(bsum, off);
    k_scan_add<<<nodeBlocks, blk, 0, stream>>>(off, bsum, cursor);
    k_fill<<<ECHUNKS * 8, blk, 0, stream>>>(src, dst, cursor, eidx);
    k_part<<<(NGRP + 256) / 256, blk, 0, stream>>>(off, part);
    k_bounds<<<1, 128, 0, stream>>>(batch, gstart);
    k_cvt<<<cvtBlocks, blk, 0, stream>>>(x, Xb, (int)(NM / 4));
    k_wcvt4<<<256, blk, 0, stream>>>(W1a, W1b, W2a, W2b, WT);

    // ---- conv1 ----
    k_gather<false><<<gatBlocks, blk, 0, stream>>>(Xb, nullptr, off, eidx, part, Ab);
    k_mlp<<<MLP_GRID, blk, 0, stream>>>(Ab, WT, b1a, WT + 16384, b1b, Yb, Srep1, N_NODES);
    k_bnfinalize<<<1, 128, 0, stream>>>(Srep1, g1, be1, SC1, N_NODES);

    // ---- conv2 (BN1+ReLU fused into gather) ----
    k_gather<true><<<gatBlocks, blk, 0, stream>>>(Yb, SC1, off, eidx, part, Ab);
    k_mlp<<<MLP_GRID, blk, 0, stream>>>(Ab, WT + 2 * 16384, b2a, WT + 3 * 16384, b2b, Xb, Srep2, N_NODES);
    k_bnfinalize<<<1, 128, 0, stream>>>(Srep2, g2, be2, SC2, N_NODES);

    // ---- pool (BN2+ReLU fused) + head ----
    k_pool<<<NGRAPH * 16, blk, 0, stream>>>(Xb, SC2, gstart, P);
    k_head<<<NGRAPH, 64, 0, stream>>>(P, gstart, Wl, bl, out);
}

// Round 9
// 403.488 us; speedup vs baseline: 1.0426x; 1.0426x over previous
//
#include <hip/hip_runtime.h>

#define N_NODES 100000
#define N_EDGESC 800000
#define HID 128
#define NGRAPH 128
#define BN_EPS 1e-5f
#define SCAN_BLOCKS ((N_NODES + 1023) / 1024)   // 98
#define NREP 32   // BN-stats atomic replicas
#define PS 136    // LDS row stride in shorts: 272B = 16B-aligned
#define MLP_GRID 782   // 1563 tiles -> 2 per block (+1 tail), ~3 blocks/CU
#define EPB 2048       // edges per fill/count block
#define ECHUNKS ((N_EDGESC + EPB - 1) / EPB)    // 391
#define NXCD 12500     // nodes per XCD partition (100000/8)

typedef __bf16 bf16x8 __attribute__((ext_vector_type(8)));
typedef float f32x4 __attribute__((ext_vector_type(4)));

__device__ inline unsigned short f2bf(float f) {     // RNE fp32 -> bf16
    unsigned int u = __float_as_uint(f);
    unsigned int r = u + 0x7FFFu + ((u >> 16) & 1u);
    return (unsigned short)(r >> 16);
}
__device__ inline float b2f(unsigned short u) {
    return __uint_as_float(((unsigned int)u) << 16);
}

// ================= CSR build (XCD-partitioned scatter) =================
__global__ __launch_bounds__(256) void k_count(const int* __restrict__ dst,
                                               int* __restrict__ deg)
{
    const int xcd = blockIdx.x & 7;
    const int chunk = blockIdx.x >> 3;
    const int lo = xcd * NXCD, hi = lo + NXCD;
    #pragma unroll
    for (int i = 0; i < EPB / 256; ++i) {
        int e = chunk * EPB + i * 256 + threadIdx.x;
        if (e < N_EDGESC) {
            int d = dst[e];
            if (d >= lo && d < hi) atomicAdd(&deg[d], 1);
        }
    }
}

__global__ __launch_bounds__(256) void k_scan_block(const int* __restrict__ deg,
    int* __restrict__ off, int* __restrict__ bsum)
{
    __shared__ int ts[256];
    int base = blockIdx.x * 1024 + threadIdx.x * 4;
    int v[4], s = 0;
    #pragma unroll
    for (int i = 0; i < 4; ++i) {
        int idx = base + i;
        v[i] = (idx < N_NODES) ? deg[idx] : 0;
        s += v[i];
    }
    ts[threadIdx.x] = s;
    __syncthreads();
    for (int d = 1; d < 256; d <<= 1) {
        int t = (threadIdx.x >= d) ? ts[threadIdx.x - d] : 0;
        __syncthreads();
        ts[threadIdx.x] += t;
        __syncthreads();
    }
    int run = ts[threadIdx.x] - s;
    #pragma unroll
    for (int i = 0; i < 4; ++i) {
        int idx = base + i;
        if (idx < N_NODES) off[idx] = run;
        run += v[i];
    }
    if (threadIdx.x == 255) bsum[blockIdx.x] = ts[255];
}

__global__ void k_scan_top(int* __restrict__ bsum, int* __restrict__ off)
{
    int run = 0;
    for (int i = 0; i < SCAN_BLOCKS; ++i) { int t = bsum[i]; bsum[i] = run; run += t; }
    off[N_NODES] = run;
}

__global__ __launch_bounds__(256) void k_scan_add(int* __restrict__ off,
    const int* __restrict__ bsum, int* __restrict__ cursor)
{
    int i = blockIdx.x * 256 + threadIdx.x;
    if (i < N_NODES) {
        int o = off[i] + bsum[i >> 10];
        off[i] = o;
        cursor[i] = o;
    }
}

__global__ __launch_bounds__(256) void k_fill(const int* __restrict__ src,
    const int* __restrict__ dst, int* __restrict__ cursor, int* __restrict__ eidx)
{
    const int xcd = blockIdx.x & 7;
    const int chunk = blockIdx.x >> 3;
    const int lo = xcd * NXCD, hi = lo + NXCD;
    #pragma unroll
    for (int i = 0; i < EPB / 256; ++i) {
        int e = chunk * EPB + i * 256 + threadIdx.x;
        if (e < N_EDGESC) {
            int d = dst[e];
            if (d >= lo && d < hi) {
                int p = atomicAdd(&cursor[d], 1);
                eidx[p] = src[e];
            }
        }
    }
}

// ================ dtype conversion ================
__global__ __launch_bounds__(256) void k_cvt(const float* __restrict__ X,
    unsigned short* __restrict__ Y, int n4)
{
    int i = blockIdx.x * 256 + threadIdx.x;
    if (i < n4) {
        float4 v = ((const float4*)X)[i];
        ((ushort4*)Y)[i] = make_ushort4(f2bf(v.x), f2bf(v.y), f2bf(v.z), f2bf(v.w));
    }
}

__global__ __launch_bounds__(256) void k_wcvt4(const float* __restrict__ Wa,
    const float* __restrict__ Wb, const float* __restrict__ Wc,
    const float* __restrict__ Wd, unsigned short* __restrict__ WT)
{
    int idx = blockIdx.x * 256 + threadIdx.x;   // 256 blocks -> 65536
    int mat = idx >> 14, w = idx & 16383;
    int k = w >> 7, n = w & 127;
    const float* W = (mat == 0) ? Wa : (mat == 1) ? Wb : (mat == 2) ? Wc : Wd;
    WT[mat * 16384 + n * 128 + k] = f2bf(W[w]);
}

// ================ gather: OUT[n] = f(X[n]) + sum f(X[j]) ================
// (R7 form — measured best) 16 lanes per node, uint4 = 8 bf16 (16B)/lane,
// 16 nodes/block, 8-way edge ILP = 128B outstanding per lane.
template<bool BN>
__device__ inline void acc_row(float* acc, uint4 v,
                               const float* sc, const float* sh)
{
    unsigned int u[4] = {v.x, v.y, v.z, v.w};
    #pragma unroll
    for (int j = 0; j < 4; ++j) {
        float lo = b2f((unsigned short)u[j]);
        float hi = b2f((unsigned short)(u[j] >> 16));
        if (BN) {
            lo = fmaxf(lo * sc[2*j]   + sh[2*j],   0.f);
            hi = fmaxf(hi * sc[2*j+1] + sh[2*j+1], 0.f);
        }
        acc[2*j]   += lo;
        acc[2*j+1] += hi;
    }
}

template<bool BN>
__global__ __launch_bounds__(256) void k_gather(
    const unsigned short* __restrict__ X, const float* __restrict__ SC,
    const int* __restrict__ off, const int* __restrict__ eidx,
    unsigned short* __restrict__ OUT, int M)
{
    int n = blockIdx.x * 16 + (threadIdx.x >> 4);
    if (n >= M) return;
    const int lane = threadIdx.x & 15;
    const size_t co = (size_t)lane * 8;

    float sc[8], sh[8];
    if (BN) {
        *(float4*)&sc[0] = ((const float4*)SC)[lane * 2];
        *(float4*)&sc[4] = ((const float4*)SC)[lane * 2 + 1];
        *(float4*)&sh[0] = ((const float4*)SC)[32 + lane * 2];
        *(float4*)&sh[4] = ((const float4*)SC)[32 + lane * 2 + 1];
    }

    float acc[8] = {0.f, 0.f, 0.f, 0.f, 0.f, 0.f, 0.f, 0.f};
    acc_row<BN>(acc, *(const uint4*)(X + (size_t)n * HID + co), sc, sh);

    int k = off[n], kend = off[n + 1];
    for (; k + 7 < kend; k += 8) {
        uint4 v0 = *(const uint4*)(X + (size_t)eidx[k]   * HID + co);
        uint4 v1 = *(const uint4*)(X + (size_t)eidx[k+1] * HID + co);
        uint4 v2 = *(const uint4*)(X + (size_t)eidx[k+2] * HID + co);
        uint4 v3 = *(const uint4*)(X + (size_t)eidx[k+3] * HID + co);
        uint4 v4 = *(const uint4*)(X + (size_t)eidx[k+4] * HID + co);
        uint4 v5 = *(const uint4*)(X + (size_t)eidx[k+5] * HID + co);
        uint4 v6 = *(const uint4*)(X + (size_t)eidx[k+6] * HID + co);
        uint4 v7 = *(const uint4*)(X + (size_t)eidx[k+7] * HID + co);
        acc_row<BN>(acc, v0, sc, sh); acc_row<BN>(acc, v1, sc, sh);
        acc_row<BN>(acc, v2, sc, sh); acc_row<BN>(acc, v3, sc, sh);
        acc_row<BN>(acc, v4, sc, sh); acc_row<BN>(acc, v5, sc, sh);
        acc_row<BN>(acc, v6, sc, sh); acc_row<BN>(acc, v7, sc, sh);
    }
    for (; k + 3 < kend; k += 4) {
        uint4 v0 = *(const uint4*)(X + (size_t)eidx[k]   * HID + co);
        uint4 v1 = *(const uint4*)(X + (size_t)eidx[k+1] * HID + co);
        uint4 v2 = *(const uint4*)(X + (size_t)eidx[k+2] * HID + co);
        uint4 v3 = *(const uint4*)(X + (size_t)eidx[k+3] * HID + co);
        acc_row<BN>(acc, v0, sc, sh); acc_row<BN>(acc, v1, sc, sh);
        acc_row<BN>(acc, v2, sc, sh); acc_row<BN>(acc, v3, sc, sh);
    }
    for (; k < kend; ++k) {
        uint4 v = *(const uint4*)(X + (size_t)eidx[k] * HID + co);
        acc_row<BN>(acc, v, sc, sh);
    }

    uint4 o;
    o.x = (unsigned int)f2bf(acc[0]) | ((unsigned int)f2bf(acc[1]) << 16);
    o.y = (unsigned int)f2bf(acc[2]) | ((unsigned int)f2bf(acc[3]) << 16);
    o.z = (unsigned int)f2bf(acc[4]) | ((unsigned int)f2bf(acc[5]) << 16);
    o.w = (unsigned int)f2bf(acc[6]) | ((unsigned int)f2bf(acc[7]) << 16);
    *(uint4*)(OUT + (size_t)n * HID + co) = o;
}

// ============== persistent fused MLP with cross-tile prefetch ==============
// Grid-stride over 64-row tiles (2 per block). Wave-private LDS; NO barriers.
__global__ __launch_bounds__(256) void k_mlp(
    const unsigned short* __restrict__ A,
    const unsigned short* __restrict__ WTa, const float* __restrict__ ba,
    const unsigned short* __restrict__ WTb, const float* __restrict__ bb,
    unsigned short* __restrict__ Cb, float* __restrict__ Srep, int M)
{
    __shared__ unsigned short Hs[4][16 * PS];

    const int tid = threadIdx.x;
    const int wave = tid >> 6;
    const int lane = tid & 63;
    const int m = lane & 15;
    const int quad = lane >> 4;
    unsigned short* lds = Hs[wave];
    const int ntiles = (M + 63) / 64;

    float bav[8], bbv[8];
    #pragma unroll
    for (int n0 = 0; n0 < 8; ++n0) { bav[n0] = ba[n0*16+m]; bbv[n0] = bb[n0*16+m]; }

    float s[8] = {0,0,0,0,0,0,0,0}, s2[8] = {0,0,0,0,0,0,0,0};

    int t = blockIdx.x;
    bf16x8 aN[4];
    if (t < ntiles) {
        const unsigned short* arow = A + (size_t)(t*64 + wave*16 + m) * HID + quad*8;
        #pragma unroll
        for (int kk = 0; kk < 4; ++kk) aN[kk] = *(const bf16x8*)(arow + kk*32);
    }

    for (; t < ntiles; t += MLP_GRID) {
        bf16x8 a[4];
        #pragma unroll
        for (int kk = 0; kk < 4; ++kk) a[kk] = aN[kk];

        int tn = t + MLP_GRID;               // prefetch next tile's A-frags
        if (tn < ntiles) {
            const unsigned short* arow = A + (size_t)(tn*64 + wave*16 + m) * HID + quad*8;
            #pragma unroll
            for (int kk = 0; kk < 4; ++kk) aN[kk] = *(const bf16x8*)(arow + kk*32);
        }

        // ---- GEMM-a ----
        f32x4 acc[8];
        #pragma unroll
        for (int n0 = 0; n0 < 8; ++n0) acc[n0] = {0.f, 0.f, 0.f, 0.f};
        #pragma unroll
        for (int kk = 0; kk < 4; ++kk) {
            #pragma unroll
            for (int n0 = 0; n0 < 8; ++n0) {
                bf16x8 b = *(const bf16x8*)(WTa + (size_t)(n0*16+m)*HID + quad*8 + kk*32);
                acc[n0] = __builtin_amdgcn_mfma_f32_16x16x32_bf16(a[kk], b, acc[n0], 0, 0, 0);
            }
        }

        // hidden = relu(acc + bias) -> wave-private LDS
        #pragma unroll
        for (int n0 = 0; n0 < 8; ++n0)
            #pragma unroll
            for (int r = 0; r < 4; ++r)
                lds[(quad*4+r)*PS + n0*16+m] = f2bf(fmaxf(acc[n0][r] + bav[n0], 0.f));
        __builtin_amdgcn_sched_barrier(0);

        bf16x8 hfr[4];
        #pragma unroll
        for (int kk = 0; kk < 4; ++kk)
            hfr[kk] = *(const bf16x8*)(lds + m*PS + quad*8 + kk*32);
        __builtin_amdgcn_sched_barrier(0);

        // ---- GEMM-b ----
        #pragma unroll
        for (int n0 = 0; n0 < 8; ++n0) acc[n0] = {0.f, 0.f, 0.f, 0.f};
        #pragma unroll
        for (int kk = 0; kk < 4; ++kk) {
            #pragma unroll
            for (int n0 = 0; n0 < 8; ++n0) {
                bf16x8 b = *(const bf16x8*)(WTb + (size_t)(n0*16+m)*HID + quad*8 + kk*32);
                acc[n0] = __builtin_amdgcn_mfma_f32_16x16x32_bf16(hfr[kk], b, acc[n0], 0, 0, 0);
            }
        }

        // ---- epilogue: bias, stats, bf16 -> LDS, coalesced store ----
        const int rowbase = t*64 + wave*16;
        bool full = (rowbase + 16 <= M);
        #pragma unroll
        for (int n0 = 0; n0 < 8; ++n0) {
            #pragma unroll
            for (int r = 0; r < 4; ++r) {
                float v = acc[n0][r] + bbv[n0];
                if (full || rowbase + quad*4 + r < M) { s[n0] += v; s2[n0] += v*v; }
                lds[(quad*4+r)*PS + n0*16+m] = f2bf(v);
            }
        }
        __builtin_amdgcn_sched_barrier(0);
        #pragma unroll
        for (int it = 0; it < 4; ++it) {
            int idx = it*64 + lane;
            int row = idx >> 4, chunk = idx & 15;
            uint4 v = *(const uint4*)(lds + row*PS + chunk*8);
            int g = rowbase + row;
            if (g < M) *(uint4*)(Cb + (size_t)g*HID + chunk*8) = v;
        }
        __builtin_amdgcn_sched_barrier(0);
    }

    // ---- once per block: reduce stats over quads, atomics into replicas ----
    #pragma unroll
    for (int n0 = 0; n0 < 8; ++n0) {
        s[n0]  += __shfl_xor(s[n0], 16, 64);
        s[n0]  += __shfl_xor(s[n0], 32, 64);
        s2[n0] += __shfl_xor(s2[n0], 16, 64);
        s2[n0] += __shfl_xor(s2[n0], 32, 64);
    }
    if (quad == 0) {
        float* R = Srep + (size_t)((blockIdx.x * 4 + wave) & (NREP - 1)) * 256;
        #pragma unroll
        for (int n0 = 0; n0 < 8; ++n0) {
            atomicAdd(&R[n0*16+m], s[n0]);
            atomicAdd(&R[128 + n0*16+m], s2[n0]);
        }
    }
}

__global__ void k_bnfinalize(const float* __restrict__ Srep,
    const float* __restrict__ gamma, const float* __restrict__ beta,
    float* __restrict__ SC, int M)
{
    int f = threadIdx.x;   // 128
    float s = 0.f, s2 = 0.f;
    for (int r = 0; r < NREP; ++r) {
        s += Srep[r * 256 + f];
        s2 += Srep[r * 256 + 128 + f];
    }
    float mean = s / (float)M;
    float var = s2 / (float)M - mean * mean;
    var = fmaxf(var, 0.f);
    float sc = gamma[f] * rsqrtf(var + BN_EPS);
    SC[f] = sc;
    SC[HID + f] = beta[f] - mean * sc;
}

// ---------------- pooling (fused BN+ReLU) ----------------
__global__ void k_bounds(const int* __restrict__ batch, int* __restrict__ gstart)
{
    int g = threadIdx.x;
    int lo = 0, hi = N_NODES;
    while (lo < hi) {
        int mid = (lo + hi) >> 1;
        if (batch[mid] < g) lo = mid + 1; else hi = mid;
    }
    gstart[g] = lo;
    if (g == 0) gstart[NGRAPH] = N_NODES;
}

__global__ __launch_bounds__(256) void k_pool(const unsigned short* __restrict__ H,
    const float* __restrict__ SC, const int* __restrict__ gstart,
    float* __restrict__ P)
{
    int g = blockIdx.x >> 4, part = blockIdx.x & 15;
    int beg = gstart[g], end = gstart[g + 1];
    int f = threadIdx.x & 127, half = threadIdx.x >> 7;
    float sc = SC[f], sh = SC[HID + f];
    float s = 0.f;
    for (int r = beg + part * 2 + half; r < end; r += 32)
        s += fmaxf(b2f(H[(size_t)r * HID + f]) * sc + sh, 0.f);
    __shared__ float ls[256];
    ls[threadIdx.x] = s;
    __syncthreads();
    if (threadIdx.x < 128)
        atomicAdd(&P[g * HID + threadIdx.x], ls[threadIdx.x] + ls[threadIdx.x + 128]);
}

// ---------------- classifier head + log_softmax ----------------
__global__ void k_head(const float* __restrict__ P, const int* __restrict__ gstart,
    const float* __restrict__ Wlin, const float* __restrict__ blin,
    float* __restrict__ out)
{
    int g = blockIdx.x;
    int l = threadIdx.x;    // 64 lanes
    float inv = 1.f / (float)max(gstart[g + 1] - gstart[g], 1);
    float p0 = P[(size_t)g * HID + l] * inv;
    float p1 = P[(size_t)g * HID + 64 + l] * inv;
    float lg[10];
    #pragma unroll
    for (int c = 0; c < 10; ++c) {
        float v = p0 * Wlin[l * 10 + c] + p1 * Wlin[(64 + l) * 10 + c];
        #pragma unroll
        for (int off = 32; off > 0; off >>= 1) v += __shfl_down(v, off);
        lg[c] = v;
    }
    if (l == 0) {
        float mx = -1e30f;
        #pragma unroll
        for (int c = 0; c < 10; ++c) { lg[c] += blin[c]; mx = fmaxf(mx, lg[c]); }
        float s = 0.f;
        #pragma unroll
        for (int c = 0; c < 10; ++c) s += expf(lg[c] - mx);
        float lse = mx + logf(s);
        #pragma unroll
        for (int c = 0; c < 10; ++c) out[g * 10 + c] = lg[c] - lse;
    }
}

extern "C" void kernel_launch(void* const* d_in, const int* in_sizes, int n_in,
                              void* d_out, int out_size, void* d_ws, size_t ws_size,
                              hipStream_t stream)
{
    const float* x    = (const float*)d_in[0];
    const int*   ei   = (const int*)d_in[1];
    const int*   batch= (const int*)d_in[2];
    const float* W1a  = (const float*)d_in[3];
    const float* b1a  = (const float*)d_in[4];
    const float* W1b  = (const float*)d_in[5];
    const float* b1b  = (const float*)d_in[6];
    const float* g1   = (const float*)d_in[7];
    const float* be1  = (const float*)d_in[8];
    const float* W2a  = (const float*)d_in[9];
    const float* b2a  = (const float*)d_in[10];
    const float* W2b  = (const float*)d_in[11];
    const float* b2b  = (const float*)d_in[12];
    const float* g2   = (const float*)d_in[13];
    const float* be2  = (const float*)d_in[14];
    const float* Wl   = (const float*)d_in[15];
    const float* bl   = (const float*)d_in[16];
    float* out = (float*)d_out;

    const int* src = ei;
    const int* dst = ei + N_EDGESC;

    const size_t NM = (size_t)N_NODES * HID;    // 12.8M
    char* wsb = (char*)d_ws;
    // Ab first: k_mlp overreads 32 rows past Ab -> lands in Yb (valid).
    unsigned short* Ab  = (unsigned short*)wsb;                 // NM u16 (agg out)
    unsigned short* Yb  = Ab + NM;                              // NM u16 (Cb1)
    unsigned short* Xb  = Yb + NM;                              // NM u16 (x / Cb2)
    // zero-init region: P, Srep1, Srep2, deg contiguous -> ONE memset
    float* P    = (float*)(Xb + NM);                            // 128*128
    float* Srep1 = P + (size_t)NGRAPH * HID;                    // NREP*256
    float* Srep2 = Srep1 + NREP * 256;                          // NREP*256
    int* deg    = (int*)(Srep2 + NREP * 256);                   // N_NODES
    float* SC1  = (float*)(deg + N_NODES);                      // 256
    float* SC2  = SC1 + 256;                                    // 256
    unsigned short* WT = (unsigned short*)(SC2 + 256);          // 4*16384 u16
    int* off    = (int*)(WT + 4 * 16384);  // N_NODES+1
    int* cursor = off + N_NODES + 1;       // N_NODES
    int* bsum   = cursor + N_NODES;        // SCAN_BLOCKS
    int* eidx   = bsum + SCAN_BLOCKS;      // N_EDGESC
    int* gstart = eidx + N_EDGESC;         // NGRAPH+1

    const size_t zeroBytes = ((size_t)NGRAPH * HID + 2 * NREP * 256) * sizeof(float)
                           + (size_t)N_NODES * sizeof(int);

    dim3 blk(256);
    const int nodeBlocks = (N_NODES + 255) / 256;      // 391
    const int gatBlocks  = (N_NODES + 15) / 16;        // 6250
    const int cvtBlocks = (int)(NM / 4 + 255) / 256;   // 12500

    // ---- CSR build + conversions ----
    hipMemsetAsync(P, 0, zeroBytes, stream);
    k_count<<<ECHUNKS * 8, blk, 0, stream>>>(dst, deg);
    k_scan_block<<<SCAN_BLOCKS, blk, 0, stream>>>(deg, off, bsum);
    k_scan_top<<<1, 1, 0, stream>>>(bsum, off);
    k_scan_add<<<nodeBlocks, blk, 0, stream>>>(off, bsum, cursor);
    k_fill<<<ECHUNKS * 8, blk, 0, stream>>>(src, dst, cursor, eidx);
    k_bounds<<<1, 128, 0, stream>>>(batch, gstart);
    k_cvt<<<cvtBlocks, blk, 0, stream>>>(x, Xb, (int)(NM / 4));
    k_wcvt4<<<256, blk, 0, stream>>>(W1a, W1b, W2a, W2b, WT);

    // ---- conv1 ----
    k_gather<false><<<gatBlocks, blk, 0, stream>>>(Xb, nullptr, off, eidx, Ab, N_NODES);
    k_mlp<<<MLP_GRID, blk, 0, stream>>>(Ab, WT, b1a, WT + 16384, b1b, Yb, Srep1, N_NODES);
    k_bnfinalize<<<1, 128, 0, stream>>>(Srep1, g1, be1, SC1, N_NODES);

    // ---- conv2 (BN1+ReLU fused into gather) ----
    k_gather<true><<<gatBlocks, blk, 0, stream>>>(Yb, SC1, off, eidx, Ab, N_NODES);
    k_mlp<<<MLP_GRID, blk, 0, stream>>>(Ab, WT + 2 * 16384, b2a, WT + 3 * 16384, b2b, Xb, Srep2, N_NODES);
    k_bnfinalize<<<1, 128, 0, stream>>>(Srep2, g2, be2, SC2, N_NODES);

    // ---- pool (BN2+ReLU fused) + head ----
    k_pool<<<NGRAPH * 16, blk, 0, stream>>>(Xb, SC2, gstart, P);
    k_head<<<NGRAPH, 64, 0, stream>>>(P, gstart, Wl, bl, out);
}